// Round 9
// baseline (103.951 us; speedup 1.0000x reference)
//
#include <hip/hip_runtime.h>
#include <math.h>

#define NPTS 8192
#define TPB 256
#define IPT 8
#define ISPAN (TPB * IPT)        // 2048 i-points per strip
#define NBLK 2048                // 8 blocks/CU x 256 CU: all co-resident, no tail
#define CPB 36                   // columns per block; 36*2048 = 73728 = total cols
#define XZ_COLS 32768            // 4 strips x 8192 j
#define TRI_COLS 20480           // sum_{s=0..3} (8192 - 2048s)

// Schraudolph exp2: 2^v ~= bitcast_f32((int)(v*2^23 + SBIAS)). Full-rate VALU
// (fma+cvt+add) instead of quarter-rate v_exp_f32 (16 cyc/wave, R3/R4).
// SBIAS centered so the multiplicative bias cancels in the log-ratio (R8:
// absmax 0.0 vs threshold 8.75e-2). v stays in [(127-120), (127+78)]*2^23.
#define SBIAS ((127.0f - 0.056915f) * 8388608.0f)

static __device__ __forceinline__ float fexp2(float v) {
    return __builtin_amdgcn_exp2f(v);   // i-side E factors only (8/thread/seg)
}

// Factored Gaussian: exp(-(|pi|^2+|pj|^2-2 dot)/ks)
//   = E(i) * 2^(dot*c1 - |pj|^2 c2),  c2=log2e/ks, c1=2c2.
// j staged with coords prescaled by c1*2^23 and w = SBIAS - |pj|^2*c2*2^23.
// Symmetry: sum_full(xx) = 2*sum_{i<j} + N (ditto zz); xz is full.
// R8->R9: IPT 4->8 — one ds_read_b128 now feeds 8 pairs (3 -> 1.5 cyc/pair
// LDS share; inner 13 -> 11.5 cyc/pair). ef/iv register arrays dropped to
// keep VGPR <= 64 (8 blocks/CU co-residency is load-balance-critical).
__global__ __launch_bounds__(TPB, 8) void itl_pairwise_kernel(
    const float* __restrict__ x, const float* __restrict__ z,
    const float* __restrict__ ks_p, float* __restrict__ partials,
    float* __restrict__ out)
{
    __shared__ float4 js[CPB];     // prescaled j coords + additive bias w
    __shared__ float red[TPB / 64];

    const int t = threadIdx.x;
    const int b = blockIdx.x;

    const float c2 = 1.44269504088896340736f / ks_p[0];  // log2(e)/ks
    const float c1K = 2.0f * c2 * 8388608.0f;
    const float c2K = c2 * 8388608.0f;

    // Folded passthrough: out[0:49152] = x || z (12288 float4, 6 per block).
    if (t < 6) {
        const int k = b * 6 + t;
        const float4* src = (k < 6144) ? ((const float4*)x + k)
                                       : ((const float4*)z + (k - 6144));
        ((float4*)out)[k] = *src;
    }

    float ssum[3] = {0.f, 0.f, 0.f};

    int c = b * CPB;
    const int cend = c + CPB;
    while (c < cend) {
        // Decode column c -> (mat, strip s, j0).
        int mat, s, j0;
        if (c < XZ_COLS) {
            mat = 0; s = c >> 13; j0 = c & 8191;
        } else {
            int ci = c - XZ_COLS;
            mat = 1;
            if (ci >= TRI_COLS) { mat = 2; ci -= TRI_COLS; }
            int s_ = 0, cum = 0;
            while (ci - cum >= NPTS - ISPAN * s_) { cum += NPTS - ISPAN * s_; ++s_; }
            s = s_;
            j0 = ISPAN * s + (ci - cum);   // strip s covers j in [2048s, 8192)
        }
        const int n = min(cend - c, NPTS - j0);

        const float* __restrict__ isrc = (mat == 2) ? z : x;
        const float* __restrict__ jsrc = (mat == 1) ? x : z;

        __syncthreads();   // protect js from previous segment's readers
        if (t < n) {
            const int j = j0 + t;
            const float a0 = jsrc[3 * j], a1 = jsrc[3 * j + 1], a2 = jsrc[3 * j + 2];
            js[t] = make_float4(a0 * c1K, a1 * c1K, a2 * c1K,
                                SBIAS - (a0 * a0 + a1 * a1 + a2 * a2) * c2K);
        }

        // i-points for strip s (8 per thread, stride TPB: coalesced).
        float p0[IPT], p1[IPT], p2[IPT];
#pragma unroll
        for (int k = 0; k < IPT; ++k) {
            const int i = s * ISPAN + t + k * TPB;
            p0[k] = isrc[3 * i]; p1[k] = isrc[3 * i + 1]; p2[k] = isrc[3 * i + 2];
        }
        __syncthreads();

        float acc[IPT];
#pragma unroll
        for (int k = 0; k < IPT; ++k) acc[k] = 0.f;

        const bool needMask = (mat != 0) && (j0 < ISPAN * (s + 1));
        if (!needMask) {
            // 1 ds_read_b128 + 8x(3 fma + cvt + add) per iter: full-rate only.
#pragma unroll 4
            for (int jj = 0; jj < n; ++jj) {
                const float4 a = js[jj];   // broadcast, conflict-free
#pragma unroll
                for (int k = 0; k < IPT; ++k) {
                    const float v = fmaf(p0[k], a.x,
                                    fmaf(p1[k], a.y,
                                    fmaf(p2[k], a.z, a.w)));
                    acc[k] += __int_as_float((int)v);
                }
            }
        } else {
            // Diagonal band: strict upper only (j > i).
#pragma unroll 2
            for (int jj = 0; jj < n; ++jj) {
                const float4 a = js[jj];
                const int j = j0 + jj;
#pragma unroll
                for (int k = 0; k < IPT; ++k) {
                    const float v = fmaf(p0[k], a.x,
                                    fmaf(p1[k], a.y,
                                    fmaf(p2[k], a.z, a.w)));
                    acc[k] += (j > s * ISPAN + t + k * TPB)
                                  ? __int_as_float((int)v) : 0.0f;
                }
            }
        }
        // Apply per-i factors E(i) (recomputed here to save 8 VGPRs in-loop).
        float segsum = 0.f;
#pragma unroll
        for (int k = 0; k < IPT; ++k) {
            const float e = fexp2(-(p0[k] * p0[k] + p1[k] * p1[k] + p2[k] * p2[k]) * c2);
            segsum = fmaf(acc[k], e, segsum);
        }
        ssum[mat] += segsum;
        c += n;
    }

    // Block reduction per matrix; partials laid out [3][NBLK].
#pragma unroll
    for (int m = 0; m < 3; ++m) {
        float v = ssum[m];
        for (int off = 32; off; off >>= 1) v += __shfl_down(v, off);
        __syncthreads();
        if ((t & 63) == 0) red[t >> 6] = v;
        __syncthreads();
        if (t == 0) partials[m * NBLK + b] = red[0] + red[1] + red[2] + red[3];
    }
}

// Reduce [3][NBLK] partials; apply symmetry (2*upper + N) and tail math.
__global__ __launch_bounds__(TPB) void itl_finalize_kernel(
    const float* __restrict__ partials, const float* __restrict__ ks_p,
    const float* __restrict__ theta_p, float* __restrict__ out_scalar)
{
    __shared__ float red[3][TPB / 64];
    const int t = threadIdx.x;
    float v0 = 0.f, v1 = 0.f, v2 = 0.f;
    for (int i = t; i < NBLK; i += TPB) {
        v0 += partials[i];
        v1 += partials[NBLK + i];
        v2 += partials[2 * NBLK + i];
    }
    for (int off = 32; off; off >>= 1) {
        v0 += __shfl_down(v0, off);
        v1 += __shfl_down(v1, off);
        v2 += __shfl_down(v2, off);
    }
    if ((t & 63) == 0) {
        red[0][t >> 6] = v0; red[1][t >> 6] = v1; red[2][t >> 6] = v2;
    }
    __syncthreads();
    if (t == 0) {
        const double Sxz = (double)(red[0][0] + red[0][1] + red[0][2] + red[0][3]);
        const double Sxx = 2.0 * (double)(red[1][0] + red[1][1] + red[1][2] + red[1][3]) + (double)NPTS;
        const double Szz = 2.0 * (double)(red[2][0] + red[2][1] + red[2][2] + red[2][3]) + (double)NPTS;
        const double inv = 1.0 / ((double)NPTS * (double)NPTS);
        const double scale = 1.0 / sqrt(2.0 * M_PI * (double)ks_p[0]);
        const double mxx = Sxx * inv * scale;
        const double mzz = Szz * inv * scale;
        const double mxz = Sxz * inv * scale;
        const double r = log(sqrt(mxx * mzz + 1e-5) / (mxz + 1e-5));
        out_scalar[0] = (float)(r * (double)theta_p[0]);
    }
}

extern "C" void kernel_launch(void* const* d_in, const int* in_sizes, int n_in,
                              void* d_out, int out_size, void* d_ws, size_t ws_size,
                              hipStream_t stream) {
    const float* x     = (const float*)d_in[0];
    const float* z     = (const float*)d_in[1];
    const float* ks    = (const float*)d_in[2];
    const float* theta = (const float*)d_in[3];
    float* out      = (float*)d_out;
    float* partials = (float*)d_ws;   // 3 * NBLK floats

    itl_pairwise_kernel<<<NBLK, TPB, 0, stream>>>(x, z, ks, partials, out);
    itl_finalize_kernel<<<1, TPB, 0, stream>>>(partials, ks, theta, out + NPTS * 3 * 2);
}

// Round 10
// 82.399 us; speedup vs baseline: 1.2616x; 1.2616x over previous
//
#include <hip/hip_runtime.h>
#include <math.h>

#define NPTS 8192
#define TPB 256
#define IPT 4
#define ISPAN (TPB * IPT)        // 1024 i-points per strip
#define NBLK 2048                // 8 blocks/CU x 256 CU: all co-resident, no tail
#define CPB 68                   // columns per block; 68*2048 = 139264 = total cols
#define XZ_COLS 65536            // 8 strips x 8192 j
#define TRI_COLS 36864           // sum_{s=0..7} (8192 - 1024s)

// Schraudolph exp2: 2^v ~= bitcast_f32((int)(v*2^23 + SBIAS)). Runs on the
// full-rate VALU (fma+cvt+add) instead of the quarter-rate trans pipe
// (v_exp_f32 = 16 cyc/wave, R3/R4 counters). SBIAS centered so the
// multiplicative bias cancels in the log-ratio (R8: absmax 0.0 vs threshold
// 8.75e-2). v stays in [(127-120), (127+78)]*2^23: no overflow/denormal.
// R9 ERRATum: IPT=8 under launch_bounds(256,8)'s 64-VGPR cap spills acc/p
// arrays to scratch (74 MB scratch WRITE, VALUBusy 0.6%, 140 us) — IPT=4 is
// the register-budget sweet spot; do not raise without relaxing occupancy.
#define SBIAS ((127.0f - 0.056915f) * 8388608.0f)

static __device__ __forceinline__ float fexp2(float v) {
    return __builtin_amdgcn_exp2f(v);   // i-side E factors only (4/thread/seg)
}

// Factored Gaussian: exp(-(|pi|^2+|pj|^2-2 dot)/ks)
//   = E(i) * 2^(dot*c1 - |pj|^2 c2),  c2=log2e/ks, c1=2c2.
// j staged with coords prescaled by c1*2^23 and w = SBIAS - |pj|^2*c2*2^23,
// so the inner pair is: v = fma(fma(fma)) ; acc += bitcast(int(v)).
// Symmetry: sum_full(xx) = 2*sum_{i<j} + N (ditto zz); xz is full.
// Work = 139264 j-columns (1 col = 1024 i x 1 j), 68/block, 2048 co-resident.
__global__ __launch_bounds__(TPB, 8) void itl_pairwise_kernel(
    const float* __restrict__ x, const float* __restrict__ z,
    const float* __restrict__ ks_p, float* __restrict__ partials,
    float* __restrict__ out)
{
    __shared__ float4 js[CPB];     // prescaled j coords + additive bias w
    __shared__ float red[TPB / 64];

    const int t = threadIdx.x;
    const int b = blockIdx.x;

    const float c2 = 1.44269504088896340736f / ks_p[0];  // log2(e)/ks
    const float c1K = 2.0f * c2 * 8388608.0f;
    const float c2K = c2 * 8388608.0f;

    // Folded passthrough: out[0:49152] = x || z (12288 float4, 6 per block).
    if (t < 6) {
        const int k = b * 6 + t;
        const float4* src = (k < 6144) ? ((const float4*)x + k)
                                       : ((const float4*)z + (k - 6144));
        ((float4*)out)[k] = *src;
    }

    float ssum[3] = {0.f, 0.f, 0.f};

    int c = b * CPB;
    const int cend = c + CPB;
    while (c < cend) {
        // Decode column c -> (mat, strip s, j0).
        int mat, s, j0;
        if (c < XZ_COLS) {
            mat = 0; s = c >> 13; j0 = c & 8191;
        } else {
            int ci = c - XZ_COLS;
            mat = 1;
            if (ci >= TRI_COLS) { mat = 2; ci -= TRI_COLS; }
            int s_ = 0, cum = 0;
            while (ci - cum >= NPTS - ISPAN * s_) { cum += NPTS - ISPAN * s_; ++s_; }
            s = s_;
            j0 = ISPAN * s + (ci - cum);   // strip s covers j in [1024s, 8192)
        }
        const int n = min(cend - c, NPTS - j0);

        const float* __restrict__ isrc = (mat == 2) ? z : x;
        const float* __restrict__ jsrc = (mat == 1) ? x : z;

        __syncthreads();   // protect js from previous segment's readers
        if (t < n) {
            const int j = j0 + t;
            const float a0 = jsrc[3 * j], a1 = jsrc[3 * j + 1], a2 = jsrc[3 * j + 2];
            js[t] = make_float4(a0 * c1K, a1 * c1K, a2 * c1K,
                                SBIAS - (a0 * a0 + a1 * a1 + a2 * a2) * c2K);
        }

        // i-points for strip s (4 per thread, stride TPB: coalesced).
        float p0[IPT], p1[IPT], p2[IPT], ef[IPT];
        int iv[IPT];
#pragma unroll
        for (int k = 0; k < IPT; ++k) {
            const int i = s * ISPAN + t + k * TPB;
            iv[k] = i;
            p0[k] = isrc[3 * i]; p1[k] = isrc[3 * i + 1]; p2[k] = isrc[3 * i + 2];
            ef[k] = fexp2(-(p0[k] * p0[k] + p1[k] * p1[k] + p2[k] * p2[k]) * c2);
        }
        __syncthreads();

        float acc[IPT] = {0.f, 0.f, 0.f, 0.f};
        const bool needMask = (mat != 0) && (j0 < ISPAN * (s + 1));
        if (!needMask) {
            // 1 ds_read_b128 + 4x(3 fma + cvt + add) per iter: full-rate only.
#pragma unroll 4
            for (int jj = 0; jj < n; ++jj) {
                const float4 a = js[jj];   // broadcast, conflict-free
#pragma unroll
                for (int k = 0; k < IPT; ++k) {
                    const float v = fmaf(p0[k], a.x,
                                    fmaf(p1[k], a.y,
                                    fmaf(p2[k], a.z, a.w)));
                    acc[k] += __int_as_float((int)v);
                }
            }
        } else {
            // Diagonal band: strict upper only (j > i).
#pragma unroll 2
            for (int jj = 0; jj < n; ++jj) {
                const float4 a = js[jj];
                const int j = j0 + jj;
#pragma unroll
                for (int k = 0; k < IPT; ++k) {
                    const float v = fmaf(p0[k], a.x,
                                    fmaf(p1[k], a.y,
                                    fmaf(p2[k], a.z, a.w)));
                    acc[k] += (j > iv[k]) ? __int_as_float((int)v) : 0.0f;
                }
            }
        }
        ssum[mat] += acc[0] * ef[0] + acc[1] * ef[1] + acc[2] * ef[2] + acc[3] * ef[3];
        c += n;
    }

    // Block reduction per matrix; partials laid out [3][NBLK].
#pragma unroll
    for (int m = 0; m < 3; ++m) {
        float v = ssum[m];
        for (int off = 32; off; off >>= 1) v += __shfl_down(v, off);
        __syncthreads();
        if ((t & 63) == 0) red[t >> 6] = v;
        __syncthreads();
        if (t == 0) partials[m * NBLK + b] = red[0] + red[1] + red[2] + red[3];
    }
}

// Reduce [3][NBLK] partials; apply symmetry (2*upper + N) and tail math.
__global__ __launch_bounds__(TPB) void itl_finalize_kernel(
    const float* __restrict__ partials, const float* __restrict__ ks_p,
    const float* __restrict__ theta_p, float* __restrict__ out_scalar)
{
    __shared__ float red[3][TPB / 64];
    const int t = threadIdx.x;
    float v0 = 0.f, v1 = 0.f, v2 = 0.f;
    for (int i = t; i < NBLK; i += TPB) {
        v0 += partials[i];
        v1 += partials[NBLK + i];
        v2 += partials[2 * NBLK + i];
    }
    for (int off = 32; off; off >>= 1) {
        v0 += __shfl_down(v0, off);
        v1 += __shfl_down(v1, off);
        v2 += __shfl_down(v2, off);
    }
    if ((t & 63) == 0) {
        red[0][t >> 6] = v0; red[1][t >> 6] = v1; red[2][t >> 6] = v2;
    }
    __syncthreads();
    if (t == 0) {
        const double Sxz = (double)(red[0][0] + red[0][1] + red[0][2] + red[0][3]);
        const double Sxx = 2.0 * (double)(red[1][0] + red[1][1] + red[1][2] + red[1][3]) + (double)NPTS;
        const double Szz = 2.0 * (double)(red[2][0] + red[2][1] + red[2][2] + red[2][3]) + (double)NPTS;
        const double inv = 1.0 / ((double)NPTS * (double)NPTS);
        const double scale = 1.0 / sqrt(2.0 * M_PI * (double)ks_p[0]);
        const double mxx = Sxx * inv * scale;
        const double mzz = Szz * inv * scale;
        const double mxz = Sxz * inv * scale;
        const double r = log(sqrt(mxx * mzz + 1e-5) / (mxz + 1e-5));
        out_scalar[0] = (float)(r * (double)theta_p[0]);
    }
}

extern "C" void kernel_launch(void* const* d_in, const int* in_sizes, int n_in,
                              void* d_out, int out_size, void* d_ws, size_t ws_size,
                              hipStream_t stream) {
    const float* x     = (const float*)d_in[0];
    const float* z     = (const float*)d_in[1];
    const float* ks    = (const float*)d_in[2];
    const float* theta = (const float*)d_in[3];
    float* out      = (float*)d_out;
    float* partials = (float*)d_ws;   // 3 * NBLK floats

    itl_pairwise_kernel<<<NBLK, TPB, 0, stream>>>(x, z, ks, partials, out);
    itl_finalize_kernel<<<1, TPB, 0, stream>>>(partials, ks, theta, out + NPTS * 3 * 2);
}